// Round 7
// baseline (124.660 us; speedup 1.0000x reference)
//
#include <hip/hip_runtime.h>
#include <hip/hip_bf16.h>

// LoRA-factored 3x3 conv. out fp32. Input dtypes runtime-detected.
// x: [16,128,56,56], A: [256,16], B: [16,1152] -> out: [16,256,56,56]
// R11: stage 1 moved to MFMA (mfma_f32_16x16x32_bf16). VALU structure
// measured-asymptote ~48us (MfmaUtil=0 all rounds); memory floor ~10us.
//  - tmp[16r x px] = Bmat[16x1152] . patch[1152 x px], M=16 = exact MFMA fit.
//  - K tap-major (k' = tap*128 + c): lane's 8 frag elems = 8 consecutive
//    channels -> 8 u16 gathers/step, 16-lane groups = 32B segments, L1/L2 hot.
//  - Bmat pre-split hi+lo bf16 in FRAG ORDER by prep (error ~2^-17, keeps
//    absmax at the bf16-x-dominated 2^-7). 2 MFMA/step, one fp32 C.
//  - Block 256 thr = 4 px-tiles = one (b,h) row; grid 56x16=896 (3.5/CU);
//    LDS 4.2KB; stage 2 = proven fp32 VALU epilogue via tmp[16][66].
// Lane maps (m89-verified C, standard A/B): A row=l&15; B col=l&15;
// k=(l>>4)*8+i; C col=l&15, row=(l>>4)*4+reg.

#define Bn 16
#define Cc 128
#define Hh 56
#define Ww 56
#define Ll (Hh * Ww)      // 3136
#define Rr 16
#define Oo 256
#define KF (Cc * 9)       // 1152
#define NKS 36            // K-steps: 1152/32

typedef __attribute__((ext_vector_type(8))) short bfrag_t;  // 8 bf16 (4 VGPR)
typedef __attribute__((ext_vector_type(4))) float f32x4;    // C frag

__device__ __forceinline__ float bf16_bits(unsigned short u) {
    return __uint_as_float(((unsigned)u) << 16);
}

__device__ __forceinline__ unsigned short bf16_rne(float f) {
    const unsigned u = __float_as_uint(f);
    const unsigned r = u + 0x7FFFu + ((u >> 16) & 1u);
    return (unsigned short)(r >> 16);
}

// bf16-packed: bits14..7 of each dword = a bf16 exponent (~[96,144]) -> 32/32.
// fp32: uniform mantissa bits -> ~6/32. Threshold 20. (Proven R3.)
__device__ __forceinline__ bool detect_bf16(const void* __restrict__ p) {
    const unsigned* w = (const unsigned*)p;
    int c = 0;
#pragma unroll
    for (int i = 0; i < 32; ++i) {
        const unsigned e = (w[i] >> 7) & 0xFFu;
        c += (e >= 96u && e <= 144u) ? 1 : 0;
    }
    return c >= 20;
}

// ---- prep: Bfrag[kstep][hi/lo][lane][8e] bf16 (frag order, tap-major K),
//      Afp[o][r] fp32. ws layout: Bfrag (73728 B) then Afp (16384 B).
__global__ __launch_bounds__(256) void prep_kernel(
    const void* __restrict__ A, const void* __restrict__ Bm,
    unsigned short* __restrict__ Bfrag, float* __restrict__ Afp)
{
    const bool ab = detect_bf16(A);
    const bool bb = detect_bf16(Bm);
    const int i = blockIdx.x * 256 + threadIdx.x;
    if (i < NKS * 512) {
        const int kstep = i >> 9, rem = i & 511;
        const int l = rem >> 3, e = rem & 7;
        const int r = l & 15, g = l >> 4;
        const int kp = kstep * 32 + g * 8 + e;   // tap-major k'
        const int tap = kp >> 7, c = kp & 127;
        const int k = c * 9 + tap;               // torch Unfold order (c,kh,kw)
        const float v = bb ? bf16_bits(((const unsigned short*)Bm)[r * KF + k])
                           : ((const float*)Bm)[r * KF + k];
        const unsigned short hi = bf16_rne(v);
        const float lov = v - bf16_bits(hi);
        Bfrag[(kstep * 2 + 0) * 512 + rem] = hi;
        Bfrag[(kstep * 2 + 1) * 512 + rem] = bf16_rne(lov);
    }
    if (i < Oo * Rr) {
        Afp[i] = ab ? bf16_bits(((const unsigned short*)A)[i])
                    : ((const float*)A)[i];
    }
}

// ---- main: one block = one (b,h) output row. 4 waves = 4 px-tiles of 16.
template<bool XB>
__device__ __forceinline__ void mfma_body(
    const void* __restrict__ x,
    const unsigned short* __restrict__ Bfrag,
    const float* __restrict__ Afp,
    float* __restrict__ out,
    float (* __restrict__ tmp)[66])
{
    const int tid  = threadIdx.x;
    const int lane = tid & 63;
    const int wv   = __builtin_amdgcn_readfirstlane(tid >> 6);  // px-tile 0..3
    const int col  = lane & 15;
    const int g    = lane >> 4;
    const int h    = blockIdx.x;
    const int b    = blockIdx.y;
    const int px   = wv * 16 + col;     // output pixel w, 0..63 (valid < 56)

    // 9 tap offsets + validity (clamped addresses, masked values)
    int  off9[9];
    bool ok9[9];
#pragma unroll
    for (int dh = 0; dh < 3; ++dh) {
        const int hr = h + dh - 1;
        const bool hok = (hr >= 0) & (hr < Hh);
        const int hc = hok ? hr : (hr < 0 ? 0 : Hh - 1);
#pragma unroll
        for (int dw = 0; dw < 3; ++dw) {
            const int wr = px + dw - 1;
            const bool wok2 = (wr >= 0) & (wr < Ww);
            const int wc = wok2 ? wr : (wr < 0 ? 0 : Ww - 1);
            off9[dh * 3 + dw] = hc * Ww + wc;
            ok9[dh * 3 + dw]  = hok & wok2;
        }
    }
    // channel-block element bases (include this lane-group's g*8 channels)
    unsigned cb4[4];
#pragma unroll
    for (int cb = 0; cb < 4; ++cb)
        cb4[cb] = (unsigned)((b * Cc + cb * 32 + g * 8) * Ll);

    f32x4 acc = {0.f, 0.f, 0.f, 0.f};
    const bfrag_t* __restrict__ bf = (const bfrag_t*)Bfrag;

#pragma unroll
    for (int ks = 0; ks < NKS; ++ks) {
        const int tap = ks >> 2, cb = ks & 3;
        const unsigned base = cb4[cb] + (unsigned)off9[tap];
        // patch fragment: 8 channel gathers (stride Ll), pack to bf16x8
        unsigned up[4];
#pragma unroll
        for (int j = 0; j < 4; ++j) {
            unsigned short v0, v1;
            if constexpr (XB) {
                v0 = ((const unsigned short*)x)[base + (unsigned)((2*j+0) * Ll)];
                v1 = ((const unsigned short*)x)[base + (unsigned)((2*j+1) * Ll)];
            } else {
                v0 = bf16_rne(((const float*)x)[base + (unsigned)((2*j+0) * Ll)]);
                v1 = bf16_rne(((const float*)x)[base + (unsigned)((2*j+1) * Ll)]);
            }
            const unsigned packed = (unsigned)v0 | ((unsigned)v1 << 16);
            up[j] = ok9[tap] ? packed : 0u;   // mask = f(tap, lane) only
        }
        union { unsigned u[4]; bfrag_t v; } pu;
        pu.u[0] = up[0]; pu.u[1] = up[1]; pu.u[2] = up[2]; pu.u[3] = up[3];
        const bfrag_t pf  = pu.v;
        const bfrag_t ahi = bf[(ks * 2 + 0) * 64 + lane];  // coalesced 16B/lane
        const bfrag_t alo = bf[(ks * 2 + 1) * 64 + lane];
        acc = __builtin_amdgcn_mfma_f32_16x16x32_bf16(ahi, pf, acc, 0, 0, 0);
        acc = __builtin_amdgcn_mfma_f32_16x16x32_bf16(alo, pf, acc, 0, 0, 0);
    }

    // C -> LDS: col=lane&15 (px), row=(lane>>4)*4+reg  [m89]
#pragma unroll
    for (int reg = 0; reg < 4; ++reg)
        tmp[g * 4 + reg][wv * 16 + col] = acc[reg];
    __syncthreads();

    // stage 2 (proven fp32 epilogue): wave wv emits o = wv*64 .. +63
    float tv[Rr];
#pragma unroll
    for (int r = 0; r < Rr; ++r) tv[r] = tmp[r][lane];   // 2-way, free

    const bool wok = (lane < Ww);
    const size_t obase = (size_t)b * Oo * Ll + (size_t)(h * Ww) + (size_t)lane;
#pragma unroll 4
    for (int j = 0; j < 64; ++j) {
        const int o = wv * 64 + j;
        const float* Ao = Afp + (size_t)o * Rr;   // uniform -> s_load
        float s = 0.f;
#pragma unroll
        for (int r = 0; r < Rr; ++r) s += Ao[r] * tv[r];
        if (wok) out[obase + (size_t)o * Ll] = s;
    }
}

__global__ __launch_bounds__(256, 4) void fused_mfma(
    const void* __restrict__ x,
    const unsigned short* __restrict__ Bfrag,
    const float* __restrict__ Afp,
    float* __restrict__ out)
{
    __shared__ float tmp[Rr][66];   // 4224 B, conflict-free both phases
    if (detect_bf16(x)) mfma_body<true >(x, Bfrag, Afp, out, tmp);
    else                mfma_body<false>(x, Bfrag, Afp, out, tmp);
}

// ---- fallback (ws too small): slow but correct, no workspace.
__global__ __launch_bounds__(256) void fused_fallback(
    const void* __restrict__ x, const void* __restrict__ A,
    const void* __restrict__ Bm, float* __restrict__ out)
{
    const bool xb = detect_bf16(x);
    const bool ab = detect_bf16(A);
    const bool bb = detect_bf16(Bm);
    const int gid = blockIdx.x * 256 + threadIdx.x;
    const int b = gid / Ll;
    const int l = gid - b * Ll;
    const int h = l / Ww, w = l - h * Ww;
    float acc[Rr];
#pragma unroll
    for (int r = 0; r < Rr; ++r) acc[r] = 0.f;
    const size_t xbase = (size_t)b * Cc * Ll;
    for (int c = 0; c < Cc; ++c) {
        const size_t xc = xbase + (size_t)c * Ll;
        float xv[9];
#pragma unroll
        for (int dh = 0; dh < 3; ++dh) {
            const int hh = h + dh - 1;
            const bool hok = (hh >= 0) & (hh < Hh);
#pragma unroll
            for (int dw = 0; dw < 3; ++dw) {
                const int ww = w + dw - 1;
                const bool ok = hok & (ww >= 0) & (ww < Ww);
                const size_t idx = xc + (size_t)(hh * Ww + ww);
                xv[dh*3+dw] = ok ? (xb ? bf16_bits(((const unsigned short*)x)[idx])
                                       : ((const float*)x)[idx]) : 0.f;
            }
        }
#pragma unroll
        for (int r = 0; r < Rr; ++r) {
            const size_t bo = (size_t)r * KF + (size_t)c * 9;
            float s = acc[r];
#pragma unroll
            for (int i = 0; i < 9; ++i)
                s += (bb ? bf16_bits(((const unsigned short*)Bm)[bo+i])
                         : ((const float*)Bm)[bo+i]) * xv[i];
            acc[r] = s;
        }
    }
    const size_t obase = (size_t)b * Oo * Ll + (size_t)l;
    for (int o = 0; o < Oo; ++o) {
        float s = 0.f;
#pragma unroll
        for (int r = 0; r < Rr; ++r)
            s += (ab ? bf16_bits(((const unsigned short*)A)[o*Rr+r])
                     : ((const float*)A)[o*Rr+r]) * acc[r];
        out[obase + (size_t)o * Ll] = s;
    }
}

extern "C" void kernel_launch(void* const* d_in, const int* in_sizes, int n_in,
                              void* d_out, int out_size, void* d_ws, size_t ws_size,
                              hipStream_t stream) {
    const void* x  = d_in[0];
    const void* A  = d_in[1];
    const void* Bm = d_in[2];
    for (int i = 0; i < n_in && i < 3; ++i) {
        const int s = in_sizes[i];
        if      (s == Bn * Cc * Ll) x  = d_in[i];
        else if (s == Oo * Rr)      A  = d_in[i];
        else if (s == Rr * KF)      Bm = d_in[i];
    }
    float* out = (float*)d_out;

    const size_t need = (size_t)(NKS * 2 * 512) * sizeof(unsigned short)  // 73728
                      + (size_t)(Oo * Rr) * sizeof(float);                // 16384
    if (ws_size >= need) {
        unsigned short* Bfrag = (unsigned short*)d_ws;
        float* Afp = (float*)((char*)d_ws + (size_t)(NKS * 2 * 512) * 2);
        prep_kernel<<<dim3(72), 256, 0, stream>>>(A, Bm, Bfrag, Afp);
        fused_mfma<<<dim3(Hh, Bn), 256, 0, stream>>>(x, Bfrag, Afp, out);
    } else {
        fused_fallback<<<dim3((Bn * Ll) / 256), 256, 0, stream>>>(x, A, Bm, out);
    }
}